// Round 2
// baseline (985.034 us; speedup 1.0000x reference)
//
#include <hip/hip_runtime.h>

#define N_NODES 50000
#define N_EDGES 800000
#define NODE_F 256
#define EDGE_F 8
#define OUT_F 64

// ---------------------------------------------------------------------------
// Kernel 1: fused node GEMMs. blockIdx.y selects which projection:
//   0: fc   = feat @ W_src.T
//   1: asrc = feat @ W_attn_src.T
//   2: adst = feat @ W_attn_dst.T
//   3: res  = feat @ W_dst.T + b_dst
// ---------------------------------------------------------------------------
__global__ __launch_bounds__(256) void node_gemm(
    const float* __restrict__ feat,
    const float* __restrict__ W_src,
    const float* __restrict__ W_attn_src,
    const float* __restrict__ W_attn_dst,
    const float* __restrict__ W_dst,
    const float* __restrict__ b_dst,
    float* __restrict__ fc, float* __restrict__ asrc,
    float* __restrict__ adst, float* __restrict__ res)
{
    const int sel = blockIdx.y;
    const float* __restrict__ W =
        sel == 0 ? W_src : sel == 1 ? W_attn_src : sel == 2 ? W_attn_dst : W_dst;
    float* __restrict__ out =
        sel == 0 ? fc : sel == 1 ? asrc : sel == 2 ? adst : res;

    __shared__ float A[64][33];
    __shared__ float B[64][33];

    const int tid = threadIdx.x;
    const int tx = tid & 15;
    const int ty = tid >> 4;
    const int m0 = blockIdx.x * 64;

    float acc[4][4] = {};

    for (int k0 = 0; k0 < NODE_F; k0 += 32) {
#pragma unroll
        for (int q = 0; q < 8; ++q) {
            int e = tid + q * 256;
            int ml = e >> 5, kl = e & 31;
            int m = m0 + ml;
            A[ml][kl] = (m < N_NODES) ? feat[(size_t)m * NODE_F + k0 + kl] : 0.f;
        }
#pragma unroll
        for (int q = 0; q < 8; ++q) {
            int e = tid + q * 256;
            int ol = e >> 5, kl = e & 31;
            B[ol][kl] = W[ol * NODE_F + k0 + kl];
        }
        __syncthreads();
#pragma unroll
        for (int kk = 0; kk < 32; ++kk) {
            float a[4], b[4];
#pragma unroll
            for (int i = 0; i < 4; ++i) a[i] = A[ty * 4 + i][kk];
#pragma unroll
            for (int j = 0; j < 4; ++j) b[j] = B[tx * 4 + j][kk];
#pragma unroll
            for (int i = 0; i < 4; ++i)
#pragma unroll
                for (int j = 0; j < 4; ++j) acc[i][j] += a[i] * b[j];
        }
        __syncthreads();
    }

#pragma unroll
    for (int i = 0; i < 4; ++i) {
        int m = m0 + ty * 4 + i;
        if (m >= N_NODES) continue;
        float4 v = make_float4(acc[i][0], acc[i][1], acc[i][2], acc[i][3]);
        if (sel == 3) {
            v.x += b_dst[tx * 4 + 0];
            v.y += b_dst[tx * 4 + 1];
            v.z += b_dst[tx * 4 + 2];
            v.w += b_dst[tx * 4 + 3];
        }
        *(float4*)&out[(size_t)m * OUT_F + tx * 4] = v;
    }
}

// ---------------------------------------------------------------------------
// CSR construction: histogram -> exclusive scan -> scatter
// ---------------------------------------------------------------------------
__global__ __launch_bounds__(256) void hist_kernel(
    const int* __restrict__ src_idx, const int* __restrict__ dst_idx,
    int* __restrict__ hist_src, int* __restrict__ hist_dst)
{
    int e = blockIdx.x * 256 + threadIdx.x;
    if (e >= N_EDGES) return;
    atomicAdd(&hist_src[src_idx[e]], 1);
    atomicAdd(&hist_dst[dst_idx[e]], 1);
}

__global__ __launch_bounds__(512) void scan_kernel(
    const int* __restrict__ hist_dst, const int* __restrict__ hist_src,
    int* __restrict__ off_dst, int* __restrict__ off_src,
    int* __restrict__ cur_dst, int* __restrict__ cur_src)
{
    const int* __restrict__ h = blockIdx.x ? hist_src : hist_dst;
    int* __restrict__ off = blockIdx.x ? off_src : off_dst;
    int* __restrict__ cur = blockIdx.x ? cur_src : cur_dst;

    __shared__ int part[512];
    const int t = threadIdx.x;
    const int CH = (N_NODES + 511) / 512;  // 98
    int lo = t * CH, hi = min(lo + CH, N_NODES);
    int sum = 0;
    for (int i = lo; i < hi; ++i) sum += h[i];
    part[t] = sum;
    __syncthreads();
    for (int ofs = 1; ofs < 512; ofs <<= 1) {
        int v = (t >= ofs) ? part[t - ofs] : 0;
        __syncthreads();
        part[t] += v;
        __syncthreads();
    }
    int run = (t == 0) ? 0 : part[t - 1];
    for (int i = lo; i < hi; ++i) {
        off[i] = run;
        cur[i] = run;
        run += h[i];
    }
    if (t == 511) off[N_NODES] = run;
}

__global__ __launch_bounds__(256) void scatter_kernel(
    const int* __restrict__ src_idx, const int* __restrict__ dst_idx,
    int* __restrict__ cur_src, int* __restrict__ cur_dst,
    int* __restrict__ eid_src, int* __restrict__ eid_dst)
{
    int e = blockIdx.x * 256 + threadIdx.x;
    if (e >= N_EDGES) return;
    int ps = atomicAdd(&cur_src[src_idx[e]], 1);
    eid_src[ps] = e;
    int pd = atomicAdd(&cur_dst[dst_idx[e]], 1);
    eid_dst[pd] = e;
}

// ---------------------------------------------------------------------------
// src pass: one 64-lane wave per src node, lane = channel.
// s_src[n][c] = sum over out-edges of exp(leaky(asrc[n]+adst[d]+ae))
// ---------------------------------------------------------------------------
__global__ __launch_bounds__(256) void src_pass(
    const int* __restrict__ off_src, const int* __restrict__ eid_src,
    const int* __restrict__ dst_idx,
    const float* __restrict__ feat_edge, const float* __restrict__ W_ae,
    const float* __restrict__ asrc, const float* __restrict__ adst,
    float* __restrict__ s_src)
{
    int n = blockIdx.x * 4 + (threadIdx.x >> 6);
    int c = threadIdx.x & 63;
    if (n >= N_NODES) return;

    float4 w0 = *(const float4*)&W_ae[c * EDGE_F];
    float4 w1 = *(const float4*)&W_ae[c * EDGE_F + 4];
    float ac = asrc[(size_t)n * OUT_F + c];

    int beg = off_src[n], end = off_src[n + 1];
    float ssum = 0.f;
    for (int i = beg; i < end; ++i) {
        int eid = eid_src[i];
        int d = dst_idx[eid];
        float4 f0 = *(const float4*)&feat_edge[(size_t)eid * EDGE_F];
        float4 f1 = *(const float4*)&feat_edge[(size_t)eid * EDGE_F + 4];
        float ae = w0.x * f0.x + w0.y * f0.y + w0.z * f0.z + w0.w * f0.w
                 + w1.x * f1.x + w1.y * f1.y + w1.z * f1.z + w1.w * f1.w;
        float e = ac + adst[(size_t)d * OUT_F + c] + ae;
        e = e > 0.f ? e : 0.2f * e;
        ssum += __expf(e);
    }
    s_src[(size_t)n * OUT_F + c] = ssum;
}

// ---------------------------------------------------------------------------
// fused dst pass: loop 1 accumulates the dst softmax denominator in registers,
// loop 2 recomputes ex (gathers are L1/L2 hot) and accumulates the message.
// No atomics anywhere.
// ---------------------------------------------------------------------------
__global__ __launch_bounds__(256) void dst_msg_pass(
    const int* __restrict__ off_dst, const int* __restrict__ eid_dst,
    const int* __restrict__ src_idx,
    const float* __restrict__ feat_edge, const float* __restrict__ W_ae,
    const float* __restrict__ asrc, const float* __restrict__ adst,
    const float* __restrict__ s_src, const float* __restrict__ fc,
    float* __restrict__ msg)
{
    int n = blockIdx.x * 4 + (threadIdx.x >> 6);
    int c = threadIdx.x & 63;
    if (n >= N_NODES) return;

    float4 w0 = *(const float4*)&W_ae[c * EDGE_F];
    float4 w1 = *(const float4*)&W_ae[c * EDGE_F + 4];
    float adc = adst[(size_t)n * OUT_F + c];

    int beg = off_dst[n], end = off_dst[n + 1];

    float sd = 0.f;
    for (int i = beg; i < end; ++i) {
        int eid = eid_dst[i];
        int s = src_idx[eid];
        float4 f0 = *(const float4*)&feat_edge[(size_t)eid * EDGE_F];
        float4 f1 = *(const float4*)&feat_edge[(size_t)eid * EDGE_F + 4];
        float ae = w0.x * f0.x + w0.y * f0.y + w0.z * f0.z + w0.w * f0.w
                 + w1.x * f1.x + w1.y * f1.y + w1.z * f1.z + w1.w * f1.w;
        float e = asrc[(size_t)s * OUT_F + c] + adc + ae;
        e = e > 0.f ? e : 0.2f * e;
        sd += __expf(e);
    }

    float rsd = (sd > 0.f) ? 1.f / sd : 0.f;
    float msum = 0.f;
    for (int i = beg; i < end; ++i) {
        int eid = eid_dst[i];
        int s = src_idx[eid];
        float4 f0 = *(const float4*)&feat_edge[(size_t)eid * EDGE_F];
        float4 f1 = *(const float4*)&feat_edge[(size_t)eid * EDGE_F + 4];
        float ae = w0.x * f0.x + w0.y * f0.y + w0.z * f0.z + w0.w * f0.w
                 + w1.x * f1.x + w1.y * f1.y + w1.z * f1.z + w1.w * f1.w;
        float e = asrc[(size_t)s * OUT_F + c] + adc + ae;
        e = e > 0.f ? e : 0.2f * e;
        float ex = __expf(e);
        float ss = s_src[(size_t)s * OUT_F + c];
        float a_d = fmaxf(ex * rsd, 1e-9f);
        float a_s = fmaxf(ex / ss, 1e-9f);
        float a = sqrtf(a_d * a_s);
        msum += fc[(size_t)s * OUT_F + c] * a;
    }
    msg[(size_t)n * OUT_F + c] = msum;
}

// ---------------------------------------------------------------------------
// per-node layernorm over 64 channels, h @ W_agg.T + b_agg + res
// ---------------------------------------------------------------------------
__global__ __launch_bounds__(256) void post_kernel(
    const float* __restrict__ msg,
    const float* __restrict__ scale, const float* __restrict__ offset,
    const float* __restrict__ W_agg, const float* __restrict__ b_agg,
    const float* __restrict__ res, float* __restrict__ out)
{
    __shared__ float hbuf[4][OUT_F];
    int t = blockIdx.x * 256 + threadIdx.x;
    int n = t >> 6;
    int c = t & 63;
    int ln = threadIdx.x >> 6;

    float x = msg[(size_t)n * OUT_F + c];
    float s1 = x, s2 = x * x;
#pragma unroll
    for (int off = 32; off; off >>= 1) {
        s1 += __shfl_xor(s1, off, 64);
        s2 += __shfl_xor(s2, off, 64);
    }
    float mean = s1 * (1.f / OUT_F);
    float var = s2 * (1.f / OUT_F) - mean * mean + 1e-9f;
    float h = (x - mean) * scale[c] * rsqrtf(var) + offset[c];
    hbuf[ln][c] = h;
    __syncthreads();

    float acc = 0.f;
#pragma unroll
    for (int j = 0; j < OUT_F; j += 4) {
        float4 w = *(const float4*)&W_agg[c * OUT_F + j];
        acc += w.x * hbuf[ln][j] + w.y * hbuf[ln][j + 1]
             + w.z * hbuf[ln][j + 2] + w.w * hbuf[ln][j + 3];
    }
    out[(size_t)n * OUT_F + c] = acc + b_agg[c] + res[(size_t)n * OUT_F + c];
}

// ---------------------------------------------------------------------------
extern "C" void kernel_launch(void* const* d_in, const int* in_sizes, int n_in,
                              void* d_out, int out_size, void* d_ws, size_t ws_size,
                              hipStream_t stream) {
    const float* feat_src    = (const float*)d_in[0];
    const float* feat_edge   = (const float*)d_in[1];
    const int*   src_idx     = (const int*)d_in[2];
    const int*   dst_idx     = (const int*)d_in[3];
    const float* W_src       = (const float*)d_in[4];
    const float* W_dst       = (const float*)d_in[5];
    const float* b_dst       = (const float*)d_in[6];
    const float* W_attn_src  = (const float*)d_in[7];
    const float* W_attn_dst  = (const float*)d_in[8];
    const float* W_attn_edge = (const float*)d_in[9];
    const float* scale       = (const float*)d_in[10];
    const float* offset      = (const float*)d_in[11];
    const float* W_agg       = (const float*)d_in[12];
    const float* b_agg       = (const float*)d_in[13];
    float* out = (float*)d_out;

    const size_t NF = (size_t)N_NODES * OUT_F;

    float* ws    = (float*)d_ws;
    float* fc    = ws;            // [N,64]
    float* asrc  = fc + NF;       // [N,64]
    float* adst  = asrc + NF;     // [N,64]
    float* res   = adst + NF;     // [N,64]
    float* s_src = res + NF;      // [N,64]
    float* msg   = s_src + NF;    // [N,64]

    int* ip        = (int*)(msg + NF);
    int* hist_dst  = ip;                    // [N]
    int* hist_src  = hist_dst + N_NODES;    // [N]
    int* off_dst   = hist_src + N_NODES;    // [N+1]
    int* off_src   = off_dst + N_NODES + 1; // [N+1]
    int* cur_dst   = off_src + N_NODES + 1; // [N]
    int* cur_src   = cur_dst + N_NODES;     // [N]
    int* eid_dst   = cur_src + N_NODES;     // [E]
    int* eid_src   = eid_dst + N_EDGES;     // [E]

    // zero the two histograms (contiguous)
    hipMemsetAsync(hist_dst, 0, 2 * N_NODES * sizeof(int), stream);

    const int eb = (N_EDGES + 255) / 256;  // 3125
    hist_kernel<<<eb, 256, 0, stream>>>(src_idx, dst_idx, hist_src, hist_dst);
    scan_kernel<<<2, 512, 0, stream>>>(hist_dst, hist_src, off_dst, off_src,
                                       cur_dst, cur_src);
    scatter_kernel<<<eb, 256, 0, stream>>>(src_idx, dst_idx, cur_src, cur_dst,
                                           eid_src, eid_dst);

    dim3 g1((N_NODES + 63) / 64, 4);
    node_gemm<<<g1, 256, 0, stream>>>(feat_src, W_src, W_attn_src, W_attn_dst,
                                      W_dst, b_dst, fc, asrc, adst, res);

    const int nb = N_NODES / 4;  // 12500
    src_pass<<<nb, 256, 0, stream>>>(off_src, eid_src, dst_idx, feat_edge,
                                     W_attn_edge, asrc, adst, s_src);
    dst_msg_pass<<<nb, 256, 0, stream>>>(off_dst, eid_dst, src_idx, feat_edge,
                                         W_attn_edge, asrc, adst, s_src, fc, msg);

    post_kernel<<<nb, 256, 0, stream>>>(msg, scale, offset, W_agg, b_agg,
                                        res, out);
}

// Round 3
// 657.999 us; speedup vs baseline: 1.4970x; 1.4970x over previous
//
#include <hip/hip_runtime.h>

#define N_NODES 50000
#define N_EDGES 800000
#define NODE_F 256
#define EDGE_F 8
#define OUT_F 64

// ---------------------------------------------------------------------------
// Kernel 1: fused node GEMMs. blockIdx.y selects projection:
//   0: fc   = feat @ W_src.T            (stride 64)
//   1: pack[:,0:64]  = feat @ W_attn_src.T   (stride 128)
//   2: adst = feat @ W_attn_dst.T       (stride 64)
//   3: res  = feat @ W_dst.T + b_dst    (stride 64)
// LDS tiles stored [k][m] (pad 68) so fragment reads are ds_read_b128.
// ---------------------------------------------------------------------------
__global__ __launch_bounds__(256) void node_gemm(
    const float* __restrict__ feat,
    const float* __restrict__ W_src,
    const float* __restrict__ W_attn_src,
    const float* __restrict__ W_attn_dst,
    const float* __restrict__ W_dst,
    const float* __restrict__ b_dst,
    float* __restrict__ fc, float* __restrict__ pack,
    float* __restrict__ adst, float* __restrict__ res)
{
    const int sel = blockIdx.y;
    const float* __restrict__ W =
        sel == 0 ? W_src : sel == 1 ? W_attn_src : sel == 2 ? W_attn_dst : W_dst;
    float* __restrict__ out =
        sel == 0 ? fc : sel == 1 ? pack : sel == 2 ? adst : res;
    const int ostride = (sel == 1) ? 128 : 64;

    __shared__ float A[32][68];   // [k][m]
    __shared__ float B[32][68];   // [k][o]

    const int tid = threadIdx.x;
    const int tx = tid & 15;      // -> 4 output cols
    const int ty = tid >> 4;      // -> 4 node rows
    const int m0 = blockIdx.x * 64;

    float acc[4][4] = {};

    for (int k0 = 0; k0 < NODE_F; k0 += 32) {
#pragma unroll
        for (int q = 0; q < 8; ++q) {
            int e = tid + q * 256;
            int ml = e >> 5, kl = e & 31;
            int m = m0 + ml;
            A[kl][ml] = (m < N_NODES) ? feat[(size_t)m * NODE_F + k0 + kl] : 0.f;
        }
#pragma unroll
        for (int q = 0; q < 8; ++q) {
            int e = tid + q * 256;
            int ol = e >> 5, kl = e & 31;
            B[kl][ol] = W[ol * NODE_F + k0 + kl];
        }
        __syncthreads();
#pragma unroll
        for (int kk = 0; kk < 32; ++kk) {
            float4 a = *(const float4*)&A[kk][ty * 4];
            float4 b = *(const float4*)&B[kk][tx * 4];
            float av[4] = {a.x, a.y, a.z, a.w};
            float bv[4] = {b.x, b.y, b.z, b.w};
#pragma unroll
            for (int i = 0; i < 4; ++i)
#pragma unroll
                for (int j = 0; j < 4; ++j) acc[i][j] += av[i] * bv[j];
        }
        __syncthreads();
    }

#pragma unroll
    for (int i = 0; i < 4; ++i) {
        int m = m0 + ty * 4 + i;
        if (m >= N_NODES) continue;
        float4 v = make_float4(acc[i][0], acc[i][1], acc[i][2], acc[i][3]);
        if (sel == 3) {
            v.x += b_dst[tx * 4 + 0];
            v.y += b_dst[tx * 4 + 1];
            v.z += b_dst[tx * 4 + 2];
            v.w += b_dst[tx * 4 + 3];
        }
        *(float4*)&out[(size_t)m * ostride + tx * 4] = v;
    }
}

// ---------------------------------------------------------------------------
// CSR construction: histogram -> exclusive scan -> scatter (also stores the
// opposite-endpoint value so the hot loops avoid a dependent indirection).
// ---------------------------------------------------------------------------
__global__ __launch_bounds__(256) void hist_kernel(
    const int* __restrict__ src_idx, const int* __restrict__ dst_idx,
    int* __restrict__ hist_src, int* __restrict__ hist_dst)
{
    int e = blockIdx.x * 256 + threadIdx.x;
    if (e >= N_EDGES) return;
    atomicAdd(&hist_src[src_idx[e]], 1);
    atomicAdd(&hist_dst[dst_idx[e]], 1);
}

__global__ __launch_bounds__(512) void scan_kernel(
    const int* __restrict__ hist_dst, const int* __restrict__ hist_src,
    int* __restrict__ off_dst, int* __restrict__ off_src,
    int* __restrict__ cur_dst, int* __restrict__ cur_src)
{
    const int* __restrict__ h = blockIdx.x ? hist_src : hist_dst;
    int* __restrict__ off = blockIdx.x ? off_src : off_dst;
    int* __restrict__ cur = blockIdx.x ? cur_src : cur_dst;

    __shared__ int part[512];
    const int t = threadIdx.x;
    const int CH = (N_NODES + 511) / 512;  // 98
    int lo = t * CH, hi = min(lo + CH, N_NODES);
    int sum = 0;
    for (int i = lo; i < hi; ++i) sum += h[i];
    part[t] = sum;
    __syncthreads();
    for (int ofs = 1; ofs < 512; ofs <<= 1) {
        int v = (t >= ofs) ? part[t - ofs] : 0;
        __syncthreads();
        part[t] += v;
        __syncthreads();
    }
    int run = (t == 0) ? 0 : part[t - 1];
    for (int i = lo; i < hi; ++i) {
        off[i] = run;
        cur[i] = run;
        run += h[i];
    }
    if (t == 511) off[N_NODES] = run;
}

__global__ __launch_bounds__(256) void scatter_kernel(
    const int* __restrict__ src_idx, const int* __restrict__ dst_idx,
    int* __restrict__ cur_src, int* __restrict__ cur_dst,
    int* __restrict__ eid_src, int* __restrict__ eid_dst,
    int* __restrict__ adj_dst, int* __restrict__ adj_src)
{
    int e = blockIdx.x * 256 + threadIdx.x;
    if (e >= N_EDGES) return;
    int s = src_idx[e], d = dst_idx[e];
    int ps = atomicAdd(&cur_src[s], 1);
    eid_src[ps] = e;
    adj_dst[ps] = d;      // dst endpoint, in src-CSR order
    int pd = atomicAdd(&cur_dst[d], 1);
    eid_dst[pd] = e;
    adj_src[pd] = s;      // src endpoint, in dst-CSR order
}

// ---------------------------------------------------------------------------
// src pass: one 64-lane wave per src node, lane = channel.
// ss = sum over out-edges of exp(leaky(asrc[n]+adst[d]+ae)); then store
// g = fc * rsqrt(ss) into pack[:,64:128].
// ---------------------------------------------------------------------------
__global__ __launch_bounds__(256) void src_pass(
    const int* __restrict__ off_src, const int* __restrict__ eid_src,
    const int* __restrict__ adj_dst,
    const float* __restrict__ feat_edge, const float* __restrict__ W_ae,
    float* __restrict__ pack, const float* __restrict__ adst,
    const float* __restrict__ fc)
{
    int n = blockIdx.x * 4 + (threadIdx.x >> 6);
    int c = threadIdx.x & 63;

    float4 w0 = *(const float4*)&W_ae[c * EDGE_F];
    float4 w1 = *(const float4*)&W_ae[c * EDGE_F + 4];
    float ac = pack[(size_t)n * 128 + c];

    int beg = off_src[n], end = off_src[n + 1];
    float ssum = 0.f;
#pragma unroll 2
    for (int i = beg; i < end; ++i) {
        int eid = eid_src[i];
        int d = adj_dst[i];
        float4 f0 = *(const float4*)&feat_edge[(size_t)eid * EDGE_F];
        float4 f1 = *(const float4*)&feat_edge[(size_t)eid * EDGE_F + 4];
        float ae = w0.x * f0.x + w0.y * f0.y + w0.z * f0.z + w0.w * f0.w
                 + w1.x * f1.x + w1.y * f1.y + w1.z * f1.z + w1.w * f1.w;
        float e = ac + adst[(size_t)d * OUT_F + c] + ae;
        e = e > 0.f ? e : 0.2f * e;
        ssum += __expf(e);
    }
    float g = (ssum > 0.f) ? fc[(size_t)n * OUT_F + c] * rsqrtf(ssum) : 0.f;
    pack[(size_t)n * 128 + 64 + c] = g;
}

// ---------------------------------------------------------------------------
// fused dst pass: ONE loop per node accumulating both
//   sd  = sum ex          and   m = sum ex * g[s]
// then msg = m * rsqrt(sd), layernorm over the wave, @W_agg.T + b_agg + res.
// ---------------------------------------------------------------------------
__global__ __launch_bounds__(256) void dst_fused_pass(
    const int* __restrict__ off_dst, const int* __restrict__ eid_dst,
    const int* __restrict__ adj_src,
    const float* __restrict__ feat_edge, const float* __restrict__ W_ae,
    const float* __restrict__ pack, const float* __restrict__ adst,
    const float* __restrict__ scale, const float* __restrict__ offset,
    const float* __restrict__ W_agg, const float* __restrict__ b_agg,
    const float* __restrict__ res, float* __restrict__ out)
{
    __shared__ float hbuf[4][OUT_F];
    int n = blockIdx.x * 4 + (threadIdx.x >> 6);
    int c = threadIdx.x & 63;
    int ln = threadIdx.x >> 6;

    float4 w0 = *(const float4*)&W_ae[c * EDGE_F];
    float4 w1 = *(const float4*)&W_ae[c * EDGE_F + 4];
    float adc = adst[(size_t)n * OUT_F + c];

    int beg = off_dst[n], end = off_dst[n + 1];
    float sd = 0.f, m = 0.f;
#pragma unroll 2
    for (int i = beg; i < end; ++i) {
        int eid = eid_dst[i];
        int s = adj_src[i];
        float asv = pack[(size_t)s * 128 + c];
        float gv  = pack[(size_t)s * 128 + 64 + c];
        float4 f0 = *(const float4*)&feat_edge[(size_t)eid * EDGE_F];
        float4 f1 = *(const float4*)&feat_edge[(size_t)eid * EDGE_F + 4];
        float ae = w0.x * f0.x + w0.y * f0.y + w0.z * f0.z + w0.w * f0.w
                 + w1.x * f1.x + w1.y * f1.y + w1.z * f1.z + w1.w * f1.w;
        float e = asv + adc + ae;
        e = e > 0.f ? e : 0.2f * e;
        float ex = __expf(e);
        sd += ex;
        m += ex * gv;
    }
    float x = (sd > 0.f) ? m * rsqrtf(sd) : 0.f;   // msg[n][c]

    // layernorm over the 64 channels of this wave
    float s1 = x, s2 = x * x;
#pragma unroll
    for (int off = 32; off; off >>= 1) {
        s1 += __shfl_xor(s1, off, 64);
        s2 += __shfl_xor(s2, off, 64);
    }
    float mean = s1 * (1.f / OUT_F);
    float var = fmaxf(s2 * (1.f / OUT_F) - mean * mean, 0.f) + 1e-9f;
    float h = (x - mean) * scale[c] * rsqrtf(var) + offset[c];
    hbuf[ln][c] = h;
    // intra-wave LDS RAW: no barrier needed (wave executes ds ops in order)

    float acc = 0.f;
#pragma unroll
    for (int j = 0; j < OUT_F; j += 4) {
        float4 w = *(const float4*)&W_agg[c * OUT_F + j];
        acc += w.x * hbuf[ln][j] + w.y * hbuf[ln][j + 1]
             + w.z * hbuf[ln][j + 2] + w.w * hbuf[ln][j + 3];
    }
    out[(size_t)n * OUT_F + c] = acc + b_agg[c] + res[(size_t)n * OUT_F + c];
}

// ---------------------------------------------------------------------------
extern "C" void kernel_launch(void* const* d_in, const int* in_sizes, int n_in,
                              void* d_out, int out_size, void* d_ws, size_t ws_size,
                              hipStream_t stream) {
    const float* feat_src    = (const float*)d_in[0];
    const float* feat_edge   = (const float*)d_in[1];
    const int*   src_idx     = (const int*)d_in[2];
    const int*   dst_idx     = (const int*)d_in[3];
    const float* W_src       = (const float*)d_in[4];
    const float* W_dst       = (const float*)d_in[5];
    const float* b_dst       = (const float*)d_in[6];
    const float* W_attn_src  = (const float*)d_in[7];
    const float* W_attn_dst  = (const float*)d_in[8];
    const float* W_attn_edge = (const float*)d_in[9];
    const float* scale       = (const float*)d_in[10];
    const float* offset      = (const float*)d_in[11];
    const float* W_agg       = (const float*)d_in[12];
    const float* b_agg       = (const float*)d_in[13];
    float* out = (float*)d_out;

    const size_t NF = (size_t)N_NODES * OUT_F;

    float* ws   = (float*)d_ws;
    float* fc   = ws;             // [N,64]
    float* adst = fc + NF;        // [N,64]
    float* res  = adst + NF;      // [N,64]
    float* pack = res + NF;       // [N,128] = {asrc | g}

    int* ip       = (int*)(pack + 2 * NF);
    int* hist_dst = ip;                     // [N]
    int* hist_src = hist_dst + N_NODES;     // [N]
    int* off_dst  = hist_src + N_NODES;     // [N+1]
    int* off_src  = off_dst + N_NODES + 1;  // [N+1]
    int* cur_dst  = off_src + N_NODES + 1;  // [N]
    int* cur_src  = cur_dst + N_NODES;      // [N]
    int* eid_dst  = cur_src + N_NODES;      // [E]
    int* eid_src  = eid_dst + N_EDGES;      // [E]
    int* adj_dst  = eid_src + N_EDGES;      // [E]
    int* adj_src  = adj_dst + N_EDGES;      // [E]

    hipMemsetAsync(hist_dst, 0, 2 * N_NODES * sizeof(int), stream);

    const int eb = (N_EDGES + 255) / 256;  // 3125
    hist_kernel<<<eb, 256, 0, stream>>>(src_idx, dst_idx, hist_src, hist_dst);
    scan_kernel<<<2, 512, 0, stream>>>(hist_dst, hist_src, off_dst, off_src,
                                       cur_dst, cur_src);
    scatter_kernel<<<eb, 256, 0, stream>>>(src_idx, dst_idx, cur_src, cur_dst,
                                           eid_src, eid_dst, adj_dst, adj_src);

    dim3 g1((N_NODES + 63) / 64, 4);
    node_gemm<<<g1, 256, 0, stream>>>(feat_src, W_src, W_attn_src, W_attn_dst,
                                      W_dst, b_dst, fc, pack, adst, res);

    const int nb = N_NODES / 4;  // 12500
    src_pass<<<nb, 256, 0, stream>>>(off_src, eid_src, adj_dst, feat_edge,
                                     W_attn_edge, pack, adst, fc);
    dst_fused_pass<<<nb, 256, 0, stream>>>(off_dst, eid_dst, adj_src, feat_edge,
                                           W_attn_edge, pack, adst, scale, offset,
                                           W_agg, b_agg, res, out);
}

// Round 4
// 636.647 us; speedup vs baseline: 1.5472x; 1.0335x over previous
//
#include <hip/hip_runtime.h>

#define N_NODES 50000
#define N_EDGES 800000
#define NODE_F 256
#define EDGE_F 8
#define OUT_F 64

typedef unsigned int u32;
typedef unsigned short u16;

// ---- bf16 helpers (RNE pack, shift unpack) --------------------------------
__device__ __forceinline__ u16 bf16r(float x) {
    u32 b = __float_as_uint(x);
    b += 0x7fffu + ((b >> 16) & 1u);
    return (u16)(b >> 16);
}
__device__ __forceinline__ u32 pk2(float a, float b) {
    return (u32)bf16r(a) | ((u32)bf16r(b) << 16);
}
__device__ __forceinline__ float bl(u32 u) { return __uint_as_float(u << 16); }
__device__ __forceinline__ float bh(u32 u) { return __uint_as_float(u & 0xffff0000u); }

// ---------------------------------------------------------------------------
// Fused node GEMM: one pass over feat computes all 4 projections.
//   fc   (f32)          = feat @ W_src.T
//   pack (u32, low16)   = bf16(feat @ W_attn_src.T)   [high16 filled later]
//   adst (bf16)         = feat @ W_attn_dst.T
//   res  (f32)          = feat @ W_dst.T + b_dst
// ---------------------------------------------------------------------------
__global__ __launch_bounds__(256) void node_gemm_fused(
    const float* __restrict__ feat,
    const float* __restrict__ W_src, const float* __restrict__ W_attn_src,
    const float* __restrict__ W_attn_dst, const float* __restrict__ W_dst,
    const float* __restrict__ b_dst,
    float* __restrict__ fc, u32* __restrict__ pack,
    u16* __restrict__ adst_bf, float* __restrict__ res)
{
    __shared__ float A[32][68];       // [k][m]
    __shared__ float B[4][32][68];    // [mat][k][o]

    const int tid = threadIdx.x;
    const int tx = tid & 15;          // 4 output cols
    const int ty = tid >> 4;          // 4 node rows
    const int m0 = blockIdx.x * 64;
    const float* Ws[4] = {W_src, W_attn_src, W_attn_dst, W_dst};

    float acc[4][16];
#pragma unroll
    for (int z = 0; z < 4; ++z)
#pragma unroll
        for (int y = 0; y < 16; ++y) acc[z][y] = 0.f;

    for (int k0 = 0; k0 < NODE_F; k0 += 32) {
#pragma unroll
        for (int q = 0; q < 8; ++q) {
            int e = tid + q * 256;
            int ml = e >> 5, kl = e & 31;
            int m = m0 + ml;
            A[kl][ml] = (m < N_NODES) ? feat[(size_t)m * NODE_F + k0 + kl] : 0.f;
        }
#pragma unroll
        for (int mat = 0; mat < 4; ++mat) {
            const float* __restrict__ W = Ws[mat];
#pragma unroll
            for (int q = 0; q < 8; ++q) {
                int e = tid + q * 256;
                int ol = e >> 5, kl = e & 31;
                B[mat][kl][ol] = W[ol * NODE_F + k0 + kl];
            }
        }
        __syncthreads();
#pragma unroll 8
        for (int kk = 0; kk < 32; ++kk) {
            float4 av = *(const float4*)&A[kk][ty * 4];
            float a[4] = {av.x, av.y, av.z, av.w};
#pragma unroll
            for (int mat = 0; mat < 4; ++mat) {
                float4 bv = *(const float4*)&B[mat][kk][tx * 4];
                float b[4] = {bv.x, bv.y, bv.z, bv.w};
#pragma unroll
                for (int i = 0; i < 4; ++i)
#pragma unroll
                    for (int j = 0; j < 4; ++j)
                        acc[mat][i * 4 + j] += a[i] * b[j];
            }
        }
        __syncthreads();
    }

    float4 bias = *(const float4*)&b_dst[tx * 4];
#pragma unroll
    for (int i = 0; i < 4; ++i) {
        int m = m0 + ty * 4 + i;
        if (m >= N_NODES) continue;
        size_t o = (size_t)m * 64 + tx * 4;
        *(float4*)&fc[o] = make_float4(acc[0][i*4], acc[0][i*4+1],
                                       acc[0][i*4+2], acc[0][i*4+3]);
        uint4 pv;
        pv.x = (u32)bf16r(acc[1][i*4+0]);
        pv.y = (u32)bf16r(acc[1][i*4+1]);
        pv.z = (u32)bf16r(acc[1][i*4+2]);
        pv.w = (u32)bf16r(acc[1][i*4+3]);
        *(uint4*)&pack[o] = pv;
        uint2 dv;
        dv.x = pk2(acc[2][i*4+0], acc[2][i*4+1]);
        dv.y = pk2(acc[2][i*4+2], acc[2][i*4+3]);
        *(uint2*)&adst_bf[o] = dv;
        *(float4*)&res[o] = make_float4(acc[3][i*4+0] + bias.x,
                                        acc[3][i*4+1] + bias.y,
                                        acc[3][i*4+2] + bias.z,
                                        acc[3][i*4+3] + bias.w);
    }
}

// ---------------------------------------------------------------------------
// CSR construction
// ---------------------------------------------------------------------------
__global__ __launch_bounds__(256) void hist_kernel(
    const int* __restrict__ src_idx, const int* __restrict__ dst_idx,
    int* __restrict__ hist_src, int* __restrict__ hist_dst)
{
    int e = blockIdx.x * 256 + threadIdx.x;
    if (e >= N_EDGES) return;
    atomicAdd(&hist_src[src_idx[e]], 1);
    atomicAdd(&hist_dst[dst_idx[e]], 1);
}

__global__ __launch_bounds__(512) void scan_kernel(
    const int* __restrict__ hist_dst, const int* __restrict__ hist_src,
    int* __restrict__ off_dst, int* __restrict__ off_src,
    int* __restrict__ cur_dst, int* __restrict__ cur_src)
{
    const int* __restrict__ h = blockIdx.x ? hist_src : hist_dst;
    int* __restrict__ off = blockIdx.x ? off_src : off_dst;
    int* __restrict__ cur = blockIdx.x ? cur_src : cur_dst;

    __shared__ int part[512];
    const int t = threadIdx.x;
    const int CH = (N_NODES + 511) / 512;
    int lo = t * CH, hi = min(lo + CH, N_NODES);
    int sum = 0;
    for (int i = lo; i < hi; ++i) sum += h[i];
    part[t] = sum;
    __syncthreads();
    for (int ofs = 1; ofs < 512; ofs <<= 1) {
        int v = (t >= ofs) ? part[t - ofs] : 0;
        __syncthreads();
        part[t] += v;
        __syncthreads();
    }
    int run = (t == 0) ? 0 : part[t - 1];
    for (int i = lo; i < hi; ++i) {
        off[i] = run;
        cur[i] = run;
        run += h[i];
    }
    if (t == 511) off[N_NODES] = run;
}

// scatter: fills adjacency value + bf16 edge features in BOTH CSR orders
__global__ __launch_bounds__(256) void scatter_kernel(
    const int* __restrict__ src_idx, const int* __restrict__ dst_idx,
    const float* __restrict__ feat_edge,
    int* __restrict__ cur_src, int* __restrict__ cur_dst,
    int* __restrict__ adj_dst, int* __restrict__ adj_src,
    uint4* __restrict__ fe_src, uint4* __restrict__ fe_dst)
{
    int e = blockIdx.x * 256 + threadIdx.x;
    if (e >= N_EDGES) return;
    int s = src_idx[e], d = dst_idx[e];
    float4 a0 = *(const float4*)&feat_edge[(size_t)e * EDGE_F];
    float4 a1 = *(const float4*)&feat_edge[(size_t)e * EDGE_F + 4];
    uint4 fv;
    fv.x = pk2(a0.x, a0.y);
    fv.y = pk2(a0.z, a0.w);
    fv.z = pk2(a1.x, a1.y);
    fv.w = pk2(a1.z, a1.w);
    int ps = atomicAdd(&cur_src[s], 1);
    adj_dst[ps] = d;
    fe_src[ps] = fv;
    int pd = atomicAdd(&cur_dst[d], 1);
    adj_src[pd] = s;
    fe_dst[pd] = fv;
}

// ---------------------------------------------------------------------------
// src pass: ss = sum_out exp(leaky(asrc[n]+adst[d]+ae));
// writes g = fc * rsqrt(ss) into high16 of pack.
// ---------------------------------------------------------------------------
#define AE_DOT(fv) (bl(fv.x)*w0 + bh(fv.x)*w1 + bl(fv.y)*w2 + bh(fv.y)*w3 + \
                    bl(fv.z)*w4 + bh(fv.z)*w5 + bl(fv.w)*w6 + bh(fv.w)*w7)

__global__ __launch_bounds__(256) void src_pass(
    const int* __restrict__ off_src, const int* __restrict__ adj_dst,
    const uint4* __restrict__ fe_src, const float* __restrict__ W_ae,
    u32* __restrict__ pack, const u16* __restrict__ adst_bf,
    const float* __restrict__ fc)
{
    int n = blockIdx.x * 4 + (threadIdx.x >> 6);
    int c = threadIdx.x & 63;

    float w0 = W_ae[c*EDGE_F+0], w1 = W_ae[c*EDGE_F+1], w2 = W_ae[c*EDGE_F+2],
          w3 = W_ae[c*EDGE_F+3], w4 = W_ae[c*EDGE_F+4], w5 = W_ae[c*EDGE_F+5],
          w6 = W_ae[c*EDGE_F+6], w7 = W_ae[c*EDGE_F+7];
    u32 uown = pack[(size_t)n * 64 + c];
    float ac = bl(uown);

    int beg = off_src[n], end = off_src[n + 1];
    float ssum = 0.f;
    int i = beg;
    for (; i + 1 < end; i += 2) {
        int d0 = adj_dst[i], d1 = adj_dst[i + 1];
        uint4 f0 = fe_src[i], f1 = fe_src[i + 1];
        float ad0 = __uint_as_float((u32)adst_bf[(size_t)d0 * 64 + c] << 16);
        float ad1 = __uint_as_float((u32)adst_bf[(size_t)d1 * 64 + c] << 16);
        float e0 = ac + ad0 + AE_DOT(f0);
        float e1 = ac + ad1 + AE_DOT(f1);
        e0 = e0 > 0.f ? e0 : 0.2f * e0;
        e1 = e1 > 0.f ? e1 : 0.2f * e1;
        ssum += __expf(e0) + __expf(e1);
    }
    if (i < end) {
        int d0 = adj_dst[i];
        uint4 f0 = fe_src[i];
        float ad0 = __uint_as_float((u32)adst_bf[(size_t)d0 * 64 + c] << 16);
        float e0 = ac + ad0 + AE_DOT(f0);
        e0 = e0 > 0.f ? e0 : 0.2f * e0;
        ssum += __expf(e0);
    }
    float g = (ssum > 0.f) ? fc[(size_t)n * 64 + c] * rsqrtf(ssum) : 0.f;
    pack[(size_t)n * 64 + c] = (uown & 0xffffu) | ((u32)bf16r(g) << 16);
}

// ---------------------------------------------------------------------------
// fused dst pass: single loop accumulates sd = Σ ex and m = Σ ex*g[s];
// msg = m * rsqrt(sd); then layernorm + @W_agg.T + b_agg + res.
// ---------------------------------------------------------------------------
__global__ __launch_bounds__(256) void dst_fused_pass(
    const int* __restrict__ off_dst, const int* __restrict__ adj_src,
    const uint4* __restrict__ fe_dst, const float* __restrict__ W_ae,
    const u32* __restrict__ pack, const u16* __restrict__ adst_bf,
    const float* __restrict__ scale, const float* __restrict__ offset,
    const float* __restrict__ W_agg, const float* __restrict__ b_agg,
    const float* __restrict__ res, float* __restrict__ out)
{
    __shared__ float hbuf[4][OUT_F];
    int n = blockIdx.x * 4 + (threadIdx.x >> 6);
    int c = threadIdx.x & 63;
    int ln = threadIdx.x >> 6;

    float w0 = W_ae[c*EDGE_F+0], w1 = W_ae[c*EDGE_F+1], w2 = W_ae[c*EDGE_F+2],
          w3 = W_ae[c*EDGE_F+3], w4 = W_ae[c*EDGE_F+4], w5 = W_ae[c*EDGE_F+5],
          w6 = W_ae[c*EDGE_F+6], w7 = W_ae[c*EDGE_F+7];
    float adc = __uint_as_float((u32)adst_bf[(size_t)n * 64 + c] << 16);

    int beg = off_dst[n], end = off_dst[n + 1];
    float sd = 0.f, mm = 0.f;
    int i = beg;
    for (; i + 1 < end; i += 2) {
        int s0 = adj_src[i], s1 = adj_src[i + 1];
        uint4 f0 = fe_dst[i], f1 = fe_dst[i + 1];
        u32 u0 = pack[(size_t)s0 * 64 + c];
        u32 u1 = pack[(size_t)s1 * 64 + c];
        float e0 = bl(u0) + adc + AE_DOT(f0);
        float e1 = bl(u1) + adc + AE_DOT(f1);
        e0 = e0 > 0.f ? e0 : 0.2f * e0;
        e1 = e1 > 0.f ? e1 : 0.2f * e1;
        float ex0 = __expf(e0), ex1 = __expf(e1);
        sd += ex0 + ex1;
        mm += ex0 * bh(u0) + ex1 * bh(u1);
    }
    if (i < end) {
        int s0 = adj_src[i];
        uint4 f0 = fe_dst[i];
        u32 u0 = pack[(size_t)s0 * 64 + c];
        float e0 = bl(u0) + adc + AE_DOT(f0);
        e0 = e0 > 0.f ? e0 : 0.2f * e0;
        float ex0 = __expf(e0);
        sd += ex0;
        mm += ex0 * bh(u0);
    }
    float x = (sd > 0.f) ? mm * rsqrtf(sd) : 0.f;   // msg[n][c]

    float s1 = x, s2 = x * x;
#pragma unroll
    for (int off = 32; off; off >>= 1) {
        s1 += __shfl_xor(s1, off, 64);
        s2 += __shfl_xor(s2, off, 64);
    }
    float mean = s1 * (1.f / OUT_F);
    float var = fmaxf(s2 * (1.f / OUT_F) - mean * mean, 0.f) + 1e-9f;
    float h = (x - mean) * scale[c] * rsqrtf(var) + offset[c];
    hbuf[ln][c] = h;
    // intra-wave LDS RAW; compiler inserts lgkmcnt

    float acc = 0.f;
#pragma unroll
    for (int j = 0; j < OUT_F; j += 4) {
        float4 w = *(const float4*)&W_agg[c * OUT_F + j];
        acc += w.x * hbuf[ln][j] + w.y * hbuf[ln][j + 1]
             + w.z * hbuf[ln][j + 2] + w.w * hbuf[ln][j + 3];
    }
    out[(size_t)n * OUT_F + c] = acc + b_agg[c] + res[(size_t)n * OUT_F + c];
}

// ---------------------------------------------------------------------------
extern "C" void kernel_launch(void* const* d_in, const int* in_sizes, int n_in,
                              void* d_out, int out_size, void* d_ws, size_t ws_size,
                              hipStream_t stream) {
    const float* feat_src    = (const float*)d_in[0];
    const float* feat_edge   = (const float*)d_in[1];
    const int*   src_idx     = (const int*)d_in[2];
    const int*   dst_idx     = (const int*)d_in[3];
    const float* W_src       = (const float*)d_in[4];
    const float* W_dst       = (const float*)d_in[5];
    const float* b_dst       = (const float*)d_in[6];
    const float* W_attn_src  = (const float*)d_in[7];
    const float* W_attn_dst  = (const float*)d_in[8];
    const float* W_attn_edge = (const float*)d_in[9];
    const float* scale       = (const float*)d_in[10];
    const float* offset      = (const float*)d_in[11];
    const float* W_agg       = (const float*)d_in[12];
    const float* b_agg       = (const float*)d_in[13];
    float* out = (float*)d_out;

    const size_t NF = (size_t)N_NODES * OUT_F;   // 3.2e6

    char* base = (char*)d_ws;
    float* fc      = (float*)base;                 base += NF * 4;
    float* res     = (float*)base;                 base += NF * 4;
    u32*   pack    = (u32*)base;                   base += NF * 4;
    uint4* fe_src  = (uint4*)base;                 base += (size_t)N_EDGES * 16;
    uint4* fe_dst  = (uint4*)base;                 base += (size_t)N_EDGES * 16;
    u16*   adst_bf = (u16*)base;                   base += NF * 2;
    int*   hist_dst = (int*)base;                  base += N_NODES * 4;
    int*   hist_src = (int*)base;                  base += N_NODES * 4;
    int*   off_dst  = (int*)base;                  base += (N_NODES + 1) * 4;
    int*   off_src  = (int*)base;                  base += (N_NODES + 1) * 4;
    int*   cur_dst  = (int*)base;                  base += N_NODES * 4;
    int*   cur_src  = (int*)base;                  base += N_NODES * 4;
    int*   adj_dst  = (int*)base;                  base += (size_t)N_EDGES * 4;
    int*   adj_src  = (int*)base;                  base += (size_t)N_EDGES * 4;

    hipMemsetAsync(hist_dst, 0, 2 * N_NODES * sizeof(int), stream);

    const int eb = (N_EDGES + 255) / 256;
    hist_kernel<<<eb, 256, 0, stream>>>(src_idx, dst_idx, hist_src, hist_dst);
    scan_kernel<<<2, 512, 0, stream>>>(hist_dst, hist_src, off_dst, off_src,
                                       cur_dst, cur_src);
    scatter_kernel<<<eb, 256, 0, stream>>>(src_idx, dst_idx, feat_edge,
                                           cur_src, cur_dst, adj_dst, adj_src,
                                           fe_src, fe_dst);

    node_gemm_fused<<<(N_NODES + 63) / 64, 256, 0, stream>>>(
        feat_src, W_src, W_attn_src, W_attn_dst, W_dst, b_dst,
        fc, pack, adst_bf, res);

    const int nb = N_NODES / 4;
    src_pass<<<nb, 256, 0, stream>>>(off_src, adj_dst, fe_src, W_attn_edge,
                                     pack, adst_bf, fc);
    dst_fused_pass<<<nb, 256, 0, stream>>>(off_dst, adj_src, fe_dst, W_attn_edge,
                                           pack, adst_bf, scale, offset,
                                           W_agg, b_agg, res, out);
}

// Round 5
// 542.916 us; speedup vs baseline: 1.8143x; 1.1726x over previous
//
#include <hip/hip_runtime.h>

#define N_NODES 50000
#define N_EDGES 800000
#define NODE_F 256
#define EDGE_F 8
#define OUT_F 64
#define M_PAD 50048   // N_NODES rounded up to 64 for tail-safe fragment loads

typedef unsigned int u32;
typedef unsigned short u16;
typedef __attribute__((ext_vector_type(8))) short bf16x8;
typedef __attribute__((ext_vector_type(4))) float f32x4;

// ---- bf16 helpers (RNE pack, shift unpack) --------------------------------
__device__ __forceinline__ u16 bf16r(float x) {
    u32 b = __float_as_uint(x);
    b += 0x7fffu + ((b >> 16) & 1u);
    return (u16)(b >> 16);
}
__device__ __forceinline__ u32 pk2(float a, float b) {
    return (u32)bf16r(a) | ((u32)bf16r(b) << 16);
}
__device__ __forceinline__ float bl(u32 u) { return __uint_as_float(u << 16); }
__device__ __forceinline__ float bh(u32 u) { return __uint_as_float(u & 0xffff0000u); }

// ---------------------------------------------------------------------------
// convert: blocks [0,6250) pack feat -> bf16; blocks [6250,6506) pack the 4
// weight matrices into Wb[256][256] bf16 (row n = mat(n>>6), out(n&63)).
// ---------------------------------------------------------------------------
__global__ __launch_bounds__(256) void convert_kernel(
    const float* __restrict__ feat,
    const float* __restrict__ W_src, const float* __restrict__ W_attn_src,
    const float* __restrict__ W_attn_dst, const float* __restrict__ W_dst,
    u16* __restrict__ feat_bf, u16* __restrict__ Wb)
{
    int b = blockIdx.x;
    if (b < 6250) {
        size_t o = ((size_t)b * 256 + threadIdx.x) * 8;   // < 12.8M
        float4 v0 = *(const float4*)&feat[o];
        float4 v1 = *(const float4*)&feat[o + 4];
        uint4 p;
        p.x = pk2(v0.x, v0.y);
        p.y = pk2(v0.z, v0.w);
        p.z = pk2(v1.x, v1.y);
        p.w = pk2(v1.z, v1.w);
        *(uint4*)&feat_bf[o] = p;
    } else {
        int t = (b - 6250) * 256 + threadIdx.x;           // < 65536
        int n = t >> 8, k = t & 255;
        int mat = n >> 6, oo = n & 63;
        const float* __restrict__ Ws[4] = {W_src, W_attn_src, W_attn_dst, W_dst};
        Wb[t] = bf16r(Ws[mat][oo * NODE_F + k]);
    }
}

// ---------------------------------------------------------------------------
// Zero-LDS MFMA GEMM: block = 64 rows, 4 waves; wave w -> output matrix w.
//   w=0: fc (f32)   w=1: pack low16 (bf16)   w=2: adst (bf16)   w=3: res+b (f32)
// A frag: lane holds feat_bf[m0 + r*16 + (lane&15)][k0 + (lane>>4)*8 .. +7]
// B frag: lane holds Wb[w*64 + n*16 + (lane&15)][k0 + (lane>>4)*8 .. +7]
// C/D: col = lane&15, row = (lane>>4)*4 + reg   (m89-verified mapping)
// ---------------------------------------------------------------------------
__global__ __launch_bounds__(256) void mfma_gemm(
    const u16* __restrict__ feat_bf, const u16* __restrict__ Wb,
    const float* __restrict__ b_dst,
    float* __restrict__ fc, u32* __restrict__ pack,
    u16* __restrict__ adst_bf, float* __restrict__ res)
{
    const int lane = threadIdx.x & 63;
    const int w = threadIdx.x >> 6;
    const int m0 = blockIdx.x * 64;
    const int lrow = lane & 15;
    const int lk = (lane >> 4) * 8;

    f32x4 acc[4][4] = {};

    const u16* Abase = feat_bf + (size_t)(m0 + lrow) * NODE_F + lk;
    const u16* Bbase = Wb + (size_t)(w * 64 + lrow) * NODE_F + lk;

#pragma unroll 2
    for (int ks = 0; ks < 8; ++ks) {
        const int k0 = ks * 32;
        bf16x8 a[4], bb[4];
#pragma unroll
        for (int r = 0; r < 4; ++r)
            a[r] = *(const bf16x8*)(Abase + (size_t)r * 16 * NODE_F + k0);
#pragma unroll
        for (int n = 0; n < 4; ++n)
            bb[n] = *(const bf16x8*)(Bbase + (size_t)n * 16 * NODE_F + k0);
#pragma unroll
        for (int r = 0; r < 4; ++r)
#pragma unroll
            for (int n = 0; n < 4; ++n)
                acc[r][n] = __builtin_amdgcn_mfma_f32_16x16x32_bf16(
                    a[r], bb[n], acc[r][n], 0, 0, 0);
    }

    const int crow0 = (lane >> 4) * 4;
    const int ccol = lane & 15;
#pragma unroll
    for (int r = 0; r < 4; ++r) {
#pragma unroll
        for (int n = 0; n < 4; ++n) {
            const int col = n * 16 + ccol;
            const float bias = b_dst[col];
#pragma unroll
            for (int j = 0; j < 4; ++j) {
                int row = m0 + r * 16 + crow0 + j;
                if (row >= N_NODES) continue;
                float v = acc[r][n][j];
                size_t o = (size_t)row * 64 + col;
                if (w == 0)      fc[o] = v;
                else if (w == 1) pack[o] = (u32)bf16r(v);
                else if (w == 2) adst_bf[o] = bf16r(v);
                else             res[o] = v + bias;
            }
        }
    }
}

// ---------------------------------------------------------------------------
// CSR construction
// ---------------------------------------------------------------------------
__global__ __launch_bounds__(256) void hist_kernel(
    const int* __restrict__ src_idx, const int* __restrict__ dst_idx,
    int* __restrict__ hist_src, int* __restrict__ hist_dst)
{
    int e = blockIdx.x * 256 + threadIdx.x;
    if (e >= N_EDGES) return;
    atomicAdd(&hist_src[src_idx[e]], 1);
    atomicAdd(&hist_dst[dst_idx[e]], 1);
}

__global__ __launch_bounds__(512) void scan_kernel(
    const int* __restrict__ hist_dst, const int* __restrict__ hist_src,
    int* __restrict__ off_dst, int* __restrict__ off_src,
    int* __restrict__ cur_dst, int* __restrict__ cur_src)
{
    const int* __restrict__ h = blockIdx.x ? hist_src : hist_dst;
    int* __restrict__ off = blockIdx.x ? off_src : off_dst;
    int* __restrict__ cur = blockIdx.x ? cur_src : cur_dst;

    __shared__ int part[512];
    const int t = threadIdx.x;
    const int CH = (N_NODES + 511) / 512;
    int lo = t * CH, hi = min(lo + CH, N_NODES);
    int sum = 0;
    for (int i = lo; i < hi; ++i) sum += h[i];
    part[t] = sum;
    __syncthreads();
    for (int ofs = 1; ofs < 512; ofs <<= 1) {
        int v = (t >= ofs) ? part[t - ofs] : 0;
        __syncthreads();
        part[t] += v;
        __syncthreads();
    }
    int run = (t == 0) ? 0 : part[t - 1];
    for (int i = lo; i < hi; ++i) {
        off[i] = run;
        cur[i] = run;
        run += h[i];
    }
    if (t == 511) off[N_NODES] = run;
}

__global__ __launch_bounds__(256) void scatter_kernel(
    const int* __restrict__ src_idx, const int* __restrict__ dst_idx,
    const float* __restrict__ feat_edge,
    int* __restrict__ cur_src, int* __restrict__ cur_dst,
    int* __restrict__ adj_dst, int* __restrict__ adj_src,
    uint4* __restrict__ fe_src, uint4* __restrict__ fe_dst)
{
    int e = blockIdx.x * 256 + threadIdx.x;
    if (e >= N_EDGES) return;
    int s = src_idx[e], d = dst_idx[e];
    float4 a0 = *(const float4*)&feat_edge[(size_t)e * EDGE_F];
    float4 a1 = *(const float4*)&feat_edge[(size_t)e * EDGE_F + 4];
    uint4 fv;
    fv.x = pk2(a0.x, a0.y);
    fv.y = pk2(a0.z, a0.w);
    fv.z = pk2(a1.x, a1.y);
    fv.w = pk2(a1.z, a1.w);
    int ps = atomicAdd(&cur_src[s], 1);
    adj_dst[ps] = d;
    fe_src[ps] = fv;
    int pd = atomicAdd(&cur_dst[d], 1);
    adj_src[pd] = s;
    fe_dst[pd] = fv;
}

// ---------------------------------------------------------------------------
// src pass: ss = sum_out exp(leaky(asrc[n]+adst[d]+ae));
// writes g = fc * rsqrt(ss) into high16 of pack.  Unrolled x4 for MLP.
// ---------------------------------------------------------------------------
#define AE_DOT(fv) (bl(fv.x)*w0 + bh(fv.x)*w1 + bl(fv.y)*w2 + bh(fv.y)*w3 + \
                    bl(fv.z)*w4 + bh(fv.z)*w5 + bl(fv.w)*w6 + bh(fv.w)*w7)

__global__ __launch_bounds__(256) void src_pass(
    const int* __restrict__ off_src, const int* __restrict__ adj_dst,
    const uint4* __restrict__ fe_src, const float* __restrict__ W_ae,
    u32* __restrict__ pack, const u16* __restrict__ adst_bf,
    const float* __restrict__ fc)
{
    int n = blockIdx.x * 4 + (threadIdx.x >> 6);
    int c = threadIdx.x & 63;

    float w0 = W_ae[c*EDGE_F+0], w1 = W_ae[c*EDGE_F+1], w2 = W_ae[c*EDGE_F+2],
          w3 = W_ae[c*EDGE_F+3], w4 = W_ae[c*EDGE_F+4], w5 = W_ae[c*EDGE_F+5],
          w6 = W_ae[c*EDGE_F+6], w7 = W_ae[c*EDGE_F+7];
    u32 uown = pack[(size_t)n * 64 + c];
    float ac = bl(uown);

    int beg = off_src[n], end = off_src[n + 1];
    float ssum = 0.f;
    int i = beg;
    for (; i + 3 < end; i += 4) {
        int d0 = adj_dst[i], d1 = adj_dst[i+1], d2 = adj_dst[i+2], d3 = adj_dst[i+3];
        uint4 f0 = fe_src[i], f1 = fe_src[i+1], f2 = fe_src[i+2], f3 = fe_src[i+3];
        float ad0 = __uint_as_float((u32)adst_bf[(size_t)d0 * 64 + c] << 16);
        float ad1 = __uint_as_float((u32)adst_bf[(size_t)d1 * 64 + c] << 16);
        float ad2 = __uint_as_float((u32)adst_bf[(size_t)d2 * 64 + c] << 16);
        float ad3 = __uint_as_float((u32)adst_bf[(size_t)d3 * 64 + c] << 16);
        float e0 = ac + ad0 + AE_DOT(f0);
        float e1 = ac + ad1 + AE_DOT(f1);
        float e2 = ac + ad2 + AE_DOT(f2);
        float e3 = ac + ad3 + AE_DOT(f3);
        e0 = e0 > 0.f ? e0 : 0.2f * e0;
        e1 = e1 > 0.f ? e1 : 0.2f * e1;
        e2 = e2 > 0.f ? e2 : 0.2f * e2;
        e3 = e3 > 0.f ? e3 : 0.2f * e3;
        ssum += __expf(e0) + __expf(e1) + __expf(e2) + __expf(e3);
    }
    for (; i < end; ++i) {
        int d0 = adj_dst[i];
        uint4 f0 = fe_src[i];
        float ad0 = __uint_as_float((u32)adst_bf[(size_t)d0 * 64 + c] << 16);
        float e0 = ac + ad0 + AE_DOT(f0);
        e0 = e0 > 0.f ? e0 : 0.2f * e0;
        ssum += __expf(e0);
    }
    float g = (ssum > 0.f) ? fc[(size_t)n * 64 + c] * rsqrtf(ssum) : 0.f;
    pack[(size_t)n * 64 + c] = (uown & 0xffffu) | ((u32)bf16r(g) << 16);
}

// ---------------------------------------------------------------------------
// fused dst pass: single loop accumulates sd = sum ex and mm = sum ex*g[s];
// msg = mm * rsqrt(sd); then layernorm + @W_agg.T + b_agg + res.
// ---------------------------------------------------------------------------
__global__ __launch_bounds__(256) void dst_fused_pass(
    const int* __restrict__ off_dst, const int* __restrict__ adj_src,
    const uint4* __restrict__ fe_dst, const float* __restrict__ W_ae,
    const u32* __restrict__ pack, const u16* __restrict__ adst_bf,
    const float* __restrict__ scale, const float* __restrict__ offset,
    const float* __restrict__ W_agg, const float* __restrict__ b_agg,
    const float* __restrict__ res, float* __restrict__ out)
{
    __shared__ float hbuf[4][OUT_F];
    int n = blockIdx.x * 4 + (threadIdx.x >> 6);
    int c = threadIdx.x & 63;
    int ln = threadIdx.x >> 6;

    float w0 = W_ae[c*EDGE_F+0], w1 = W_ae[c*EDGE_F+1], w2 = W_ae[c*EDGE_F+2],
          w3 = W_ae[c*EDGE_F+3], w4 = W_ae[c*EDGE_F+4], w5 = W_ae[c*EDGE_F+5],
          w6 = W_ae[c*EDGE_F+6], w7 = W_ae[c*EDGE_F+7];
    float adc = __uint_as_float((u32)adst_bf[(size_t)n * 64 + c] << 16);

    int beg = off_dst[n], end = off_dst[n + 1];
    float sd = 0.f, mm = 0.f;
    int i = beg;
    for (; i + 3 < end; i += 4) {
        int s0 = adj_src[i], s1 = adj_src[i+1], s2 = adj_src[i+2], s3 = adj_src[i+3];
        uint4 f0 = fe_dst[i], f1 = fe_dst[i+1], f2 = fe_dst[i+2], f3 = fe_dst[i+3];
        u32 u0 = pack[(size_t)s0 * 64 + c];
        u32 u1 = pack[(size_t)s1 * 64 + c];
        u32 u2 = pack[(size_t)s2 * 64 + c];
        u32 u3 = pack[(size_t)s3 * 64 + c];
        float e0 = bl(u0) + adc + AE_DOT(f0);
        float e1 = bl(u1) + adc + AE_DOT(f1);
        float e2 = bl(u2) + adc + AE_DOT(f2);
        float e3 = bl(u3) + adc + AE_DOT(f3);
        e0 = e0 > 0.f ? e0 : 0.2f * e0;
        e1 = e1 > 0.f ? e1 : 0.2f * e1;
        e2 = e2 > 0.f ? e2 : 0.2f * e2;
        e3 = e3 > 0.f ? e3 : 0.2f * e3;
        float ex0 = __expf(e0), ex1 = __expf(e1), ex2 = __expf(e2), ex3 = __expf(e3);
        sd += ex0 + ex1 + ex2 + ex3;
        mm += ex0 * bh(u0) + ex1 * bh(u1) + ex2 * bh(u2) + ex3 * bh(u3);
    }
    for (; i < end; ++i) {
        int s0 = adj_src[i];
        uint4 f0 = fe_dst[i];
        u32 u0 = pack[(size_t)s0 * 64 + c];
        float e0 = bl(u0) + adc + AE_DOT(f0);
        e0 = e0 > 0.f ? e0 : 0.2f * e0;
        float ex0 = __expf(e0);
        sd += ex0;
        mm += ex0 * bh(u0);
    }
    float x = (sd > 0.f) ? mm * rsqrtf(sd) : 0.f;   // msg[n][c]

    float s1 = x, s2 = x * x;
#pragma unroll
    for (int off = 32; off; off >>= 1) {
        s1 += __shfl_xor(s1, off, 64);
        s2 += __shfl_xor(s2, off, 64);
    }
    float mean = s1 * (1.f / OUT_F);
    float var = fmaxf(s2 * (1.f / OUT_F) - mean * mean, 0.f) + 1e-9f;
    float h = (x - mean) * scale[c] * rsqrtf(var) + offset[c];
    hbuf[ln][c] = h;
    // intra-wave LDS RAW; compiler inserts lgkmcnt

    float acc = 0.f;
#pragma unroll
    for (int j = 0; j < OUT_F; j += 4) {
        float4 w = *(const float4*)&W_agg[c * OUT_F + j];
        acc += w.x * hbuf[ln][j] + w.y * hbuf[ln][j + 1]
             + w.z * hbuf[ln][j + 2] + w.w * hbuf[ln][j + 3];
    }
    out[(size_t)n * OUT_F + c] = acc + b_agg[c] + res[(size_t)n * OUT_F + c];
}

// ---------------------------------------------------------------------------
extern "C" void kernel_launch(void* const* d_in, const int* in_sizes, int n_in,
                              void* d_out, int out_size, void* d_ws, size_t ws_size,
                              hipStream_t stream) {
    const float* feat_src    = (const float*)d_in[0];
    const float* feat_edge   = (const float*)d_in[1];
    const int*   src_idx     = (const int*)d_in[2];
    const int*   dst_idx     = (const int*)d_in[3];
    const float* W_src       = (const float*)d_in[4];
    const float* W_dst       = (const float*)d_in[5];
    const float* b_dst       = (const float*)d_in[6];
    const float* W_attn_src  = (const float*)d_in[7];
    const float* W_attn_dst  = (const float*)d_in[8];
    const float* W_attn_edge = (const float*)d_in[9];
    const float* scale       = (const float*)d_in[10];
    const float* offset      = (const float*)d_in[11];
    const float* W_agg       = (const float*)d_in[12];
    const float* b_agg       = (const float*)d_in[13];
    float* out = (float*)d_out;

    const size_t NF = (size_t)N_NODES * OUT_F;   // 3.2e6

    char* base = (char*)d_ws;
    float* fc      = (float*)base;                 base += NF * 4;
    float* res     = (float*)base;                 base += NF * 4;
    u32*   pack    = (u32*)base;                   base += NF * 4;
    u16*   feat_bf = (u16*)base;                   base += (size_t)M_PAD * NODE_F * 2;
    u16*   Wb      = (u16*)base;                   base += 256 * 256 * 2;
    uint4* fe_src  = (uint4*)base;                 base += (size_t)N_EDGES * 16;
    uint4* fe_dst  = (uint4*)base;                 base += (size_t)N_EDGES * 16;
    u16*   adst_bf = (u16*)base;                   base += NF * 2;
    int*   hist_dst = (int*)base;                  base += N_NODES * 4;
    int*   hist_src = (int*)base;                  base += N_NODES * 4;
    int*   off_dst  = (int*)base;                  base += (N_NODES + 1) * 4;
    int*   off_src  = (int*)base;                  base += (N_NODES + 1) * 4;
    int*   cur_dst  = (int*)base;                  base += N_NODES * 4;
    int*   cur_src  = (int*)base;                  base += N_NODES * 4;
    int*   adj_dst  = (int*)base;                  base += (size_t)N_EDGES * 4;
    int*   adj_src  = (int*)base;                  base += (size_t)N_EDGES * 4;

    hipMemsetAsync(hist_dst, 0, 2 * N_NODES * sizeof(int), stream);

    const int eb = (N_EDGES + 255) / 256;
    hist_kernel<<<eb, 256, 0, stream>>>(src_idx, dst_idx, hist_src, hist_dst);
    scan_kernel<<<2, 512, 0, stream>>>(hist_dst, hist_src, off_dst, off_src,
                                       cur_dst, cur_src);
    scatter_kernel<<<eb, 256, 0, stream>>>(src_idx, dst_idx, feat_edge,
                                           cur_src, cur_dst, adj_dst, adj_src,
                                           fe_src, fe_dst);

    convert_kernel<<<6250 + 256, 256, 0, stream>>>(
        feat_src, W_src, W_attn_src, W_attn_dst, W_dst, feat_bf, Wb);

    mfma_gemm<<<M_PAD / 64, 256, 0, stream>>>(feat_bf, Wb, b_dst,
                                              fc, pack, adst_bf, res);

    const int nb = N_NODES / 4;
    src_pass<<<nb, 256, 0, stream>>>(off_src, adj_dst, fe_src, W_attn_edge,
                                     pack, adst_bf, fc);
    dst_fused_pass<<<nb, 256, 0, stream>>>(off_dst, adj_src, fe_dst, W_attn_edge,
                                           pack, adst_bf, scale, offset,
                                           W_agg, b_agg, res, out);
}

// Round 6
// 451.684 us; speedup vs baseline: 2.1808x; 1.2020x over previous
//
#include <hip/hip_runtime.h>

#define N_NODES 50000
#define N_EDGES 800000
#define NODE_F 256
#define EDGE_F 8
#define OUT_F 64
#define M_PAD 50048         // N_NODES rounded to 64
#define GEMM_BLOCKS 782     // M_PAD / 64
#define EDGE_BLOCKS 3125    // N_EDGES / 256
#define FEAT_BLOCKS 6250    // N_NODES*NODE_F / (256*8)

typedef unsigned int u32;
typedef unsigned short u16;
typedef __attribute__((ext_vector_type(8))) short bf16x8;
typedef __attribute__((ext_vector_type(4))) float f32x4;
typedef __attribute__((ext_vector_type(2))) _Float16 h2;

// ---- bf16 helpers ---------------------------------------------------------
__device__ __forceinline__ u16 bf16r(float x) {
    u32 b = __float_as_uint(x);
    b += 0x7fffu + ((b >> 16) & 1u);
    return (u16)(b >> 16);
}
__device__ __forceinline__ u32 pk2(float a, float b) {
    return (u32)bf16r(a) | ((u32)bf16r(b) << 16);
}
__device__ __forceinline__ float bl(u32 u) { return __uint_as_float(u << 16); }
__device__ __forceinline__ float bh(u32 u) { return __uint_as_float(u & 0xffff0000u); }

// ---- f16 helpers ----------------------------------------------------------
__device__ __forceinline__ u32 pkh2(float a, float b) {
    union { h2 h; u32 u; } cv;
    cv.h[0] = (_Float16)a; cv.h[1] = (_Float16)b;
    return cv.u;
}
__device__ __forceinline__ h2 uh2(u32 u) {
    union { u32 u; h2 h; } cv; cv.u = u; return cv.h;
}
__device__ __forceinline__ float ae_dot(uint4 f, h2 w0, h2 w1, h2 w2, h2 w3) {
#if __has_builtin(__builtin_amdgcn_fdot2)
    float r = __builtin_amdgcn_fdot2(uh2(f.x), w0, 0.f, false);
    r = __builtin_amdgcn_fdot2(uh2(f.y), w1, r, false);
    r = __builtin_amdgcn_fdot2(uh2(f.z), w2, r, false);
    r = __builtin_amdgcn_fdot2(uh2(f.w), w3, r, false);
    return r;
#else
    h2 a0 = uh2(f.x), a1 = uh2(f.y), a2 = uh2(f.z), a3 = uh2(f.w);
    return (float)a0[0]*(float)w0[0] + (float)a0[1]*(float)w0[1]
         + (float)a1[0]*(float)w1[0] + (float)a1[1]*(float)w1[1]
         + (float)a2[0]*(float)w2[0] + (float)a2[1]*(float)w2[1]
         + (float)a3[0]*(float)w3[0] + (float)a3[1]*(float)w3[1];
#endif
}
#define LOAD_WH(c)                                                         \
    h2 wh0, wh1, wh2, wh3;                                                 \
    {                                                                      \
        float4 wa = *(const float4*)&W_ae[(c) * EDGE_F];                   \
        float4 wb = *(const float4*)&W_ae[(c) * EDGE_F + 4];               \
        wh0[0] = (_Float16)wa.x; wh0[1] = (_Float16)wa.y;                  \
        wh1[0] = (_Float16)wa.z; wh1[1] = (_Float16)wa.w;                  \
        wh2[0] = (_Float16)wb.x; wh2[1] = (_Float16)wb.y;                  \
        wh3[0] = (_Float16)wb.z; wh3[1] = (_Float16)wb.w;                  \
    }

// ---------------------------------------------------------------------------
// K1: fused {feat->bf16 convert | 4 weights->Wb bf16 | degree histograms}
// ---------------------------------------------------------------------------
__global__ __launch_bounds__(256) void hist_convert(
    const int* __restrict__ src_idx, const int* __restrict__ dst_idx,
    const float* __restrict__ feat,
    const float* __restrict__ W_src, const float* __restrict__ W_attn_src,
    const float* __restrict__ W_attn_dst, const float* __restrict__ W_dst,
    int* __restrict__ hist_src, int* __restrict__ hist_dst,
    u16* __restrict__ feat_bf, u16* __restrict__ Wb)
{
    int b = blockIdx.x;
    if (b < FEAT_BLOCKS) {
        size_t o = ((size_t)b * 256 + threadIdx.x) * 8;
        float4 v0 = *(const float4*)&feat[o];
        float4 v1 = *(const float4*)&feat[o + 4];
        uint4 p;
        p.x = pk2(v0.x, v0.y);
        p.y = pk2(v0.z, v0.w);
        p.z = pk2(v1.x, v1.y);
        p.w = pk2(v1.z, v1.w);
        *(uint4*)&feat_bf[o] = p;
    } else if (b < FEAT_BLOCKS + 256) {
        int t = (b - FEAT_BLOCKS) * 256 + threadIdx.x;    // < 65536
        int n = t >> 8, k = t & 255;
        int mat = n >> 6, oo = n & 63;
        const float* __restrict__ Ws[4] = {W_src, W_attn_src, W_attn_dst, W_dst};
        Wb[t] = bf16r(Ws[mat][oo * NODE_F + k]);
    } else {
        int e = (b - FEAT_BLOCKS - 256) * 256 + threadIdx.x;
        if (e >= N_EDGES) return;
        atomicAdd(&hist_src[src_idx[e]], 1);
        atomicAdd(&hist_dst[dst_idx[e]], 1);
    }
}

// ---------------------------------------------------------------------------
// K2: two-array exclusive scan
// ---------------------------------------------------------------------------
__global__ __launch_bounds__(512) void scan_kernel(
    const int* __restrict__ hist_dst, const int* __restrict__ hist_src,
    int* __restrict__ off_dst, int* __restrict__ off_src,
    int* __restrict__ cur_dst, int* __restrict__ cur_src)
{
    const int* __restrict__ h = blockIdx.x ? hist_src : hist_dst;
    int* __restrict__ off = blockIdx.x ? off_src : off_dst;
    int* __restrict__ cur = blockIdx.x ? cur_src : cur_dst;

    __shared__ int part[512];
    const int t = threadIdx.x;
    const int CH = (N_NODES + 511) / 512;
    int lo = t * CH, hi = min(lo + CH, N_NODES);
    int sum = 0;
    for (int i = lo; i < hi; ++i) sum += h[i];
    part[t] = sum;
    __syncthreads();
    for (int ofs = 1; ofs < 512; ofs <<= 1) {
        int v = (t >= ofs) ? part[t - ofs] : 0;
        __syncthreads();
        part[t] += v;
        __syncthreads();
    }
    int run = (t == 0) ? 0 : part[t - 1];
    for (int i = lo; i < hi; ++i) {
        off[i] = run;
        cur[i] = run;
        run += h[i];
    }
    if (t == 511) off[N_NODES] = run;
}

// ---------------------------------------------------------------------------
// K3: fused {zero-LDS MFMA GEMM | CSR scatter}.
// GEMM: block = 64 rows, 4 waves; wave w -> output matrix w.
//   w=0: fc (f32)  w=1: pack low16 (bf16)  w=2: adst (bf16)  w=3: res+b (f32)
// Scatter: adjacency value + f16 edge features in both CSR orders.
// ---------------------------------------------------------------------------
__global__ __launch_bounds__(256) void gemm_scatter(
    const u16* __restrict__ feat_bf, const u16* __restrict__ Wb,
    const float* __restrict__ b_dst,
    float* __restrict__ fc, u32* __restrict__ pack,
    u16* __restrict__ adst_bf, float* __restrict__ res,
    const int* __restrict__ src_idx, const int* __restrict__ dst_idx,
    const float* __restrict__ feat_edge,
    int* __restrict__ cur_src, int* __restrict__ cur_dst,
    int* __restrict__ adj_dst, int* __restrict__ adj_src,
    uint4* __restrict__ fh_src, uint4* __restrict__ fh_dst)
{
    if (blockIdx.x < GEMM_BLOCKS) {
        const int lane = threadIdx.x & 63;
        const int w = threadIdx.x >> 6;
        const int m0 = blockIdx.x * 64;
        const int lrow = lane & 15;
        const int lk = (lane >> 4) * 8;

        f32x4 acc[4][4] = {};
        const u16* Abase = feat_bf + (size_t)(m0 + lrow) * NODE_F + lk;
        const u16* Bbase = Wb + (size_t)(w * 64 + lrow) * NODE_F + lk;

#pragma unroll 2
        for (int ks = 0; ks < 8; ++ks) {
            const int k0 = ks * 32;
            bf16x8 a[4], bb[4];
#pragma unroll
            for (int r = 0; r < 4; ++r)
                a[r] = *(const bf16x8*)(Abase + (size_t)r * 16 * NODE_F + k0);
#pragma unroll
            for (int n = 0; n < 4; ++n)
                bb[n] = *(const bf16x8*)(Bbase + (size_t)n * 16 * NODE_F + k0);
#pragma unroll
            for (int r = 0; r < 4; ++r)
#pragma unroll
                for (int n = 0; n < 4; ++n)
                    acc[r][n] = __builtin_amdgcn_mfma_f32_16x16x32_bf16(
                        a[r], bb[n], acc[r][n], 0, 0, 0);
        }

        const int crow0 = (lane >> 4) * 4;
        const int ccol = lane & 15;
#pragma unroll
        for (int r = 0; r < 4; ++r) {
#pragma unroll
            for (int n = 0; n < 4; ++n) {
                const int col = n * 16 + ccol;
                const float bias = b_dst[col];
#pragma unroll
                for (int j = 0; j < 4; ++j) {
                    int row = m0 + r * 16 + crow0 + j;
                    if (row >= N_NODES) continue;
                    float v = acc[r][n][j];
                    size_t o = (size_t)row * 64 + col;
                    if (w == 0)      fc[o] = v;
                    else if (w == 1) pack[o] = (u32)bf16r(v);
                    else if (w == 2) adst_bf[o] = bf16r(v);
                    else             res[o] = v + bias;
                }
            }
        }
    } else {
        int e = (blockIdx.x - GEMM_BLOCKS) * 256 + threadIdx.x;
        if (e >= N_EDGES) return;
        int s = src_idx[e], d = dst_idx[e];
        float4 a0 = *(const float4*)&feat_edge[(size_t)e * EDGE_F];
        float4 a1 = *(const float4*)&feat_edge[(size_t)e * EDGE_F + 4];
        uint4 fv;
        fv.x = pkh2(a0.x, a0.y);
        fv.y = pkh2(a0.z, a0.w);
        fv.z = pkh2(a1.x, a1.y);
        fv.w = pkh2(a1.z, a1.w);
        int ps = atomicAdd(&cur_src[s], 1);
        adj_dst[ps] = d;
        fh_src[ps] = fv;
        int pd = atomicAdd(&cur_dst[d], 1);
        adj_src[pd] = s;
        fh_dst[pd] = fv;
    }
}

// ---------------------------------------------------------------------------
// src pass: ss = sum_out exp(leaky(asrc[n]+adst[d]+ae));
// writes g = fc * rsqrt(ss) into high16 of pack.
// Loop bounds readfirstlane'd so adj/fh loads compile to scalar loads.
// ---------------------------------------------------------------------------
__global__ __launch_bounds__(256) void src_pass(
    const int* __restrict__ off_src, const int* __restrict__ adj_dst,
    const uint4* __restrict__ fh_src, const float* __restrict__ W_ae,
    u32* __restrict__ pack, const u16* __restrict__ adst_bf,
    const float* __restrict__ fc)
{
    int n = blockIdx.x * 4 + (threadIdx.x >> 6);
    int c = threadIdx.x & 63;

    LOAD_WH(c);
    u32 uown = pack[(size_t)n * 64 + c];
    float ac = bl(uown);

    int beg = __builtin_amdgcn_readfirstlane(off_src[n]);
    int end = __builtin_amdgcn_readfirstlane(off_src[n + 1]);
    float ssum = 0.f;
    int i = beg;
    for (; i + 3 < end; i += 4) {
        int d0 = adj_dst[i], d1 = adj_dst[i+1], d2 = adj_dst[i+2], d3 = adj_dst[i+3];
        uint4 f0 = fh_src[i], f1 = fh_src[i+1], f2 = fh_src[i+2], f3 = fh_src[i+3];
        float ad0 = __uint_as_float((u32)adst_bf[(size_t)d0 * 64 + c] << 16);
        float ad1 = __uint_as_float((u32)adst_bf[(size_t)d1 * 64 + c] << 16);
        float ad2 = __uint_as_float((u32)adst_bf[(size_t)d2 * 64 + c] << 16);
        float ad3 = __uint_as_float((u32)adst_bf[(size_t)d3 * 64 + c] << 16);
        float e0 = ac + ad0 + ae_dot(f0, wh0, wh1, wh2, wh3);
        float e1 = ac + ad1 + ae_dot(f1, wh0, wh1, wh2, wh3);
        float e2 = ac + ad2 + ae_dot(f2, wh0, wh1, wh2, wh3);
        float e3 = ac + ad3 + ae_dot(f3, wh0, wh1, wh2, wh3);
        e0 = fmaxf(e0, 0.2f * e0);
        e1 = fmaxf(e1, 0.2f * e1);
        e2 = fmaxf(e2, 0.2f * e2);
        e3 = fmaxf(e3, 0.2f * e3);
        ssum += __expf(e0) + __expf(e1) + __expf(e2) + __expf(e3);
    }
    for (; i < end; ++i) {
        int d0 = adj_dst[i];
        uint4 f0 = fh_src[i];
        float ad0 = __uint_as_float((u32)adst_bf[(size_t)d0 * 64 + c] << 16);
        float e0 = ac + ad0 + ae_dot(f0, wh0, wh1, wh2, wh3);
        e0 = fmaxf(e0, 0.2f * e0);
        ssum += __expf(e0);
    }
    float g = (ssum > 0.f) ? fc[(size_t)n * 64 + c] * rsqrtf(ssum) : 0.f;
    pack[(size_t)n * 64 + c] = (uown & 0xffffu) | ((u32)bf16r(g) << 16);
}

// ---------------------------------------------------------------------------
// fused dst pass: single loop accumulates sd = sum ex, mm = sum ex*g[s];
// msg = mm*rsqrt(sd); layernorm + @W_agg.T + b_agg + res.
// ---------------------------------------------------------------------------
__global__ __launch_bounds__(256) void dst_fused_pass(
    const int* __restrict__ off_dst, const int* __restrict__ adj_src,
    const uint4* __restrict__ fh_dst, const float* __restrict__ W_ae,
    const u32* __restrict__ pack, const u16* __restrict__ adst_bf,
    const float* __restrict__ scale, const float* __restrict__ offset,
    const float* __restrict__ W_agg, const float* __restrict__ b_agg,
    const float* __restrict__ res, float* __restrict__ out)
{
    __shared__ float hbuf[4][OUT_F];
    int n = blockIdx.x * 4 + (threadIdx.x >> 6);
    int c = threadIdx.x & 63;
    int ln = threadIdx.x >> 6;

    LOAD_WH(c);
    float adc = __uint_as_float((u32)adst_bf[(size_t)n * 64 + c] << 16);

    int beg = __builtin_amdgcn_readfirstlane(off_dst[n]);
    int end = __builtin_amdgcn_readfirstlane(off_dst[n + 1]);
    float sd = 0.f, mm = 0.f;
    int i = beg;
    for (; i + 3 < end; i += 4) {
        int s0 = adj_src[i], s1 = adj_src[i+1], s2 = adj_src[i+2], s3 = adj_src[i+3];
        uint4 f0 = fh_dst[i], f1 = fh_dst[i+1], f2 = fh_dst[i+2], f3 = fh_dst[i+3];
        u32 u0 = pack[(size_t)s0 * 64 + c];
        u32 u1 = pack[(size_t)s1 * 64 + c];
        u32 u2 = pack[(size_t)s2 * 64 + c];
        u32 u3 = pack[(size_t)s3 * 64 + c];
        float e0 = bl(u0) + adc + ae_dot(f0, wh0, wh1, wh2, wh3);
        float e1 = bl(u1) + adc + ae_dot(f1, wh0, wh1, wh2, wh3);
        float e2 = bl(u2) + adc + ae_dot(f2, wh0, wh1, wh2, wh3);
        float e3 = bl(u3) + adc + ae_dot(f3, wh0, wh1, wh2, wh3);
        e0 = fmaxf(e0, 0.2f * e0);
        e1 = fmaxf(e1, 0.2f * e1);
        e2 = fmaxf(e2, 0.2f * e2);
        e3 = fmaxf(e3, 0.2f * e3);
        float ex0 = __expf(e0), ex1 = __expf(e1), ex2 = __expf(e2), ex3 = __expf(e3);
        sd += ex0 + ex1 + ex2 + ex3;
        mm += ex0 * bh(u0) + ex1 * bh(u1) + ex2 * bh(u2) + ex3 * bh(u3);
    }
    for (; i < end; ++i) {
        int s0 = adj_src[i];
        uint4 f0 = fh_dst[i];
        u32 u0 = pack[(size_t)s0 * 64 + c];
        float e0 = bl(u0) + adc + ae_dot(f0, wh0, wh1, wh2, wh3);
        e0 = fmaxf(e0, 0.2f * e0);
        float ex0 = __expf(e0);
        sd += ex0;
        mm += ex0 * bh(u0);
    }
    float x = (sd > 0.f) ? mm * rsqrtf(sd) : 0.f;   // msg[n][c]

    float s1 = x, s2 = x * x;
#pragma unroll
    for (int off = 32; off; off >>= 1) {
        s1 += __shfl_xor(s1, off, 64);
        s2 += __shfl_xor(s2, off, 64);
    }
    float mean = s1 * (1.f / OUT_F);
    float var = fmaxf(s2 * (1.f / OUT_F) - mean * mean, 0.f) + 1e-9f;
    float h = (x - mean) * scale[c] * rsqrtf(var) + offset[c];
    hbuf[ln][c] = h;
    // intra-wave LDS RAW; compiler inserts lgkmcnt

    float acc = 0.f;
#pragma unroll
    for (int j = 0; j < OUT_F; j += 4) {
        float4 w = *(const float4*)&W_agg[c * OUT_F + j];
        acc += w.x * hbuf[ln][j] + w.y * hbuf[ln][j + 1]
             + w.z * hbuf[ln][j + 2] + w.w * hbuf[ln][j + 3];
    }
    out[(size_t)n * OUT_F + c] = acc + b_agg[c] + res[(size_t)n * OUT_F + c];
}

// ---------------------------------------------------------------------------
extern "C" void kernel_launch(void* const* d_in, const int* in_sizes, int n_in,
                              void* d_out, int out_size, void* d_ws, size_t ws_size,
                              hipStream_t stream) {
    const float* feat_src    = (const float*)d_in[0];
    const float* feat_edge   = (const float*)d_in[1];
    const int*   src_idx     = (const int*)d_in[2];
    const int*   dst_idx     = (const int*)d_in[3];
    const float* W_src       = (const float*)d_in[4];
    const float* W_dst       = (const float*)d_in[5];
    const float* b_dst       = (const float*)d_in[6];
    const float* W_attn_src  = (const float*)d_in[7];
    const float* W_attn_dst  = (const float*)d_in[8];
    const float* W_attn_edge = (const float*)d_in[9];
    const float* scale       = (const float*)d_in[10];
    const float* offset      = (const float*)d_in[11];
    const float* W_agg       = (const float*)d_in[12];
    const float* b_agg       = (const float*)d_in[13];
    float* out = (float*)d_out;

    const size_t NF = (size_t)N_NODES * OUT_F;   // 3.2e6

    char* base = (char*)d_ws;
    float* fc      = (float*)base;                 base += NF * 4;
    float* res     = (float*)base;                 base += NF * 4;
    u32*   pack    = (u32*)base;                   base += NF * 4;
    u16*   feat_bf = (u16*)base;                   base += (size_t)M_PAD * NODE_F * 2;
    u16*   Wb      = (u16*)base;                   base += 256 * 256 * 2;
    uint4* fh_src  = (uint4*)base;                 base += (size_t)N_EDGES * 16;
    uint4* fh_dst  = (uint4*)base;                 base += (size_t)N_EDGES * 16;
    u16*   adst_bf = (u16*)base;                   base += NF * 2;
    int*   hist_dst = (int*)base;                  base += N_NODES * 4;
    int*   hist_src = (int*)base;                  base += N_NODES * 4;
    int*   off_dst  = (int*)base;                  base += (N_NODES + 1) * 4;
    int*   off_src  = (int*)base;                  base += (N_NODES + 1) * 4;
    int*   cur_dst  = (int*)base;                  base += N_NODES * 4;
    int*   cur_src  = (int*)base;                  base += N_NODES * 4;
    int*   adj_dst  = (int*)base;                  base += (size_t)N_EDGES * 4;
    int*   adj_src  = (int*)base;                  base += (size_t)N_EDGES * 4;

    hipMemsetAsync(hist_dst, 0, 2 * N_NODES * sizeof(int), stream);

    hist_convert<<<FEAT_BLOCKS + 256 + EDGE_BLOCKS, 256, 0, stream>>>(
        src_idx, dst_idx, feat_src, W_src, W_attn_src, W_attn_dst, W_dst,
        hist_src, hist_dst, feat_bf, Wb);

    scan_kernel<<<2, 512, 0, stream>>>(hist_dst, hist_src, off_dst, off_src,
                                       cur_dst, cur_src);

    gemm_scatter<<<GEMM_BLOCKS + EDGE_BLOCKS, 256, 0, stream>>>(
        feat_bf, Wb, b_dst, fc, pack, adst_bf, res,
        src_idx, dst_idx, feat_edge, cur_src, cur_dst,
        adj_dst, adj_src, fh_src, fh_dst);

    const int nb = N_NODES / 4;
    src_pass<<<nb, 256, 0, stream>>>(off_src, adj_dst, fh_src, W_attn_edge,
                                     pack, adst_bf, fc);
    dst_fused_pass<<<nb, 256, 0, stream>>>(off_dst, adj_src, fh_dst, W_attn_edge,
                                           pack, adst_bf, scale, offset,
                                           W_agg, b_agg, res, out);
}